// Round 1
// baseline (209.465 us; speedup 1.0000x reference)
//
#include <hip/hip_runtime.h>
#include <math.h>

#define B  8
#define T  16
#define C  64
#define H  56
#define W  56
#define HW (H*W)          // 3136
#define HW4 (HW/4)        // 784
#define DS 8
#define DIN (DS*DS)       // 64
#define DOUT 32
#define BC (B*C)          // 512

typedef float vfloat4 __attribute__((ext_vector_type(4)));

// ---------------------------------------------------------------------------
// Fully fused: pool + q/k + softmax + apply in ONE kernel.
// One block per n = b*C+c (512 blocks, 256 threads = 4 waves).
// LDS ~75 KB -> 2 blocks/CU, all 512 blocks resident.
//
// Phase A: stage 4 t-slices (50 KB) at a time; each thread reduces one 7x7
//          window (2-way bank pattern = free).
// Phase B: q/k (64->32), 16x16 logits, softmax -> att_tr[s][t] (transposed,
//          stride 16 so phase C reads 4 coefficients per ds_read_b128
//          broadcast; softmax writes land on distinct banks r+16(s&1)).
// Phase C: out[t, col] = sum_s att[t][s] * x[s, col]. Each wave owns ALL 16
//          t's for its columns (acc[16] float4 = 64 VGPR) -> no duplicated
//          x loads between waves (the old apply kernel loaded every x value
//          twice). s-loop unroll 4 bounds live xv/att regs (~160 VGPR total,
//          fits the __launch_bounds__(256,2) 256-VGPR cap with margin).
//          x re-read here is L3-warm (x = 102.8 MB < 256 MB LLC, phase A just
//          streamed it). Non-temporal stores keep out from evicting x.
// ---------------------------------------------------------------------------
__global__ __launch_bounds__(256, 2) void fused_kernel(const float* __restrict__ x,
                                                       const float* __restrict__ Wq,
                                                       const float* __restrict__ bq,
                                                       const float* __restrict__ Wk,
                                                       const float* __restrict__ bk,
                                                       float* __restrict__ out) {
    __shared__ float xs[4 * HW];          // 50176 B
    __shared__ float pooled_s[T * DIN];   // 4 KB
    __shared__ float wq_s[DIN * DOUT];    // 8 KB
    __shared__ float wk_s[DIN * DOUT];    // 8 KB
    __shared__ float qs[T * 33];          // padded stride 33
    __shared__ float ks[T * 33];          // padded stride 33
    __shared__ float att_s[T * T];        // logits
    __shared__ float att_tr[T * T];       // att transposed: [s][t], stride 16

    const int n = blockIdx.x;             // b*C + c
    const int tid = threadIdx.x;
    const int b = n >> 6;
    const int c = n & 63;

    // stage weights while we pool
    for (int e = tid; e < DIN * DOUT; e += 256) { wq_s[e] = Wq[e]; wk_s[e] = Wk[e]; }

    const float4* x4 = (const float4*)x;
    float4* xs4 = (float4*)xs;

    // ---- Phase A: pool, 4 t-slices per group ----
    #pragma unroll 1
    for (int g = 0; g < 4; ++g) {
        for (int i = tid; i < 4 * HW4; i += 256) {
            const int ti = i / HW4;       // const divisor -> magic mul
            const int p  = i - ti * HW4;
            xs4[i] = x4[((size_t)(b * T + g * 4 + ti) * C + c) * HW4 + p];
        }
        __syncthreads();
        {
            const int ti  = tid >> 6;     // wave -> t-slice
            const int wi  = tid & 63;     // window index = ri*8+rj
            const int ri  = wi >> 3;
            const int rj  = wi & 7;
            float s = 0.f;
            const int base = ti * HW + (7 * ri) * W + 7 * rj;
            #pragma unroll
            for (int di = 0; di < 7; ++di) {
                #pragma unroll
                for (int dj = 0; dj < 7; ++dj) s += xs[base + di * W + dj];
            }
            pooled_s[(g * 4 + ti) * DIN + wi] = s * (1.0f / 49.0f);
        }
        __syncthreads();
    }

    // ---- Phase B: q,k ----
    for (int e = tid; e < T * DOUT; e += 256) {
        const int t = e >> 5;
        const int d = e & 31;
        float sq = bq[d];
        float sk = bk[d];
        #pragma unroll
        for (int kk = 0; kk < DIN; ++kk) {
            const float f = pooled_s[t * DIN + kk];
            sq = fmaf(f, wq_s[kk * DOUT + d], sq);
            sk = fmaf(f, wk_s[kk * DOUT + d], sk);
        }
        qs[t * 33 + d] = sq;
        ks[t * 33 + d] = sk;
    }
    __syncthreads();

    // logits (one per thread)
    {
        const int tt = tid >> 4;
        const int ss = tid & 15;
        float s = 0.f;
        #pragma unroll
        for (int d = 0; d < DOUT; ++d) s = fmaf(qs[tt * 33 + d], ks[ss * 33 + d], s);
        att_s[tid] = s * 0.25f;           // 1/sqrt(16)
    }
    __syncthreads();

    // softmax rows (16 threads), write TRANSPOSED for phase C b128 reads
    if (tid < T) {
        const int r = tid;
        float m = -INFINITY;
        #pragma unroll
        for (int s = 0; s < T; ++s) m = fmaxf(m, att_s[r * T + s]);
        float e[T];
        float sum = 0.f;
        #pragma unroll
        for (int s = 0; s < T; ++s) { e[s] = __expf(att_s[r * T + s] - m); sum += e[s]; }
        const float inv = 1.0f / sum;
        #pragma unroll
        for (int s = 0; s < T; ++s) att_tr[s * T + r] = e[s] * inv;  // banks r+16(s&1): conflict-free
    }
    __syncthreads();

    // ---- Phase C: apply. out[t,col] = sum_s att_tr[s][t] * x[s,col] ----
    const float4* att4 = (const float4*)att_tr;   // att4[s*4+q].{x..w} = att[t=4q+j][s]
    float4* o4 = (float4*)out;
    const size_t xbase = ((size_t)(b * T) * C + c) * HW4;
    const size_t tstride = (size_t)C * HW4;       // float4 stride between t-slices

    #pragma unroll 1
    for (int i = tid; i < HW4; i += 256) {
        float4 acc[16];
        #pragma unroll
        for (int t = 0; t < 16; ++t) acc[t] = make_float4(0.f, 0.f, 0.f, 0.f);

        #pragma unroll 4
        for (int s = 0; s < T; ++s) {
            const float4 xv = x4[xbase + (size_t)s * tstride + i];
            #pragma unroll
            for (int q = 0; q < 4; ++q) {
                const float4 a = att4[s * 4 + q];   // broadcast ds_read_b128
                acc[q*4+0].x = fmaf(a.x, xv.x, acc[q*4+0].x);
                acc[q*4+0].y = fmaf(a.x, xv.y, acc[q*4+0].y);
                acc[q*4+0].z = fmaf(a.x, xv.z, acc[q*4+0].z);
                acc[q*4+0].w = fmaf(a.x, xv.w, acc[q*4+0].w);
                acc[q*4+1].x = fmaf(a.y, xv.x, acc[q*4+1].x);
                acc[q*4+1].y = fmaf(a.y, xv.y, acc[q*4+1].y);
                acc[q*4+1].z = fmaf(a.y, xv.z, acc[q*4+1].z);
                acc[q*4+1].w = fmaf(a.y, xv.w, acc[q*4+1].w);
                acc[q*4+2].x = fmaf(a.z, xv.x, acc[q*4+2].x);
                acc[q*4+2].y = fmaf(a.z, xv.y, acc[q*4+2].y);
                acc[q*4+2].z = fmaf(a.z, xv.z, acc[q*4+2].z);
                acc[q*4+2].w = fmaf(a.z, xv.w, acc[q*4+2].w);
                acc[q*4+3].x = fmaf(a.w, xv.x, acc[q*4+3].x);
                acc[q*4+3].y = fmaf(a.w, xv.y, acc[q*4+3].y);
                acc[q*4+3].z = fmaf(a.w, xv.z, acc[q*4+3].z);
                acc[q*4+3].w = fmaf(a.w, xv.w, acc[q*4+3].w);
            }
        }

        #pragma unroll
        for (int t = 0; t < 16; ++t) {
            vfloat4* dst = (vfloat4*)&o4[xbase + (size_t)t * tstride + i];
            vfloat4 v; v.x = acc[t].x; v.y = acc[t].y; v.z = acc[t].z; v.w = acc[t].w;
            __builtin_nontemporal_store(v, dst);
        }
    }
}

extern "C" void kernel_launch(void* const* d_in, const int* in_sizes, int n_in,
                              void* d_out, int out_size, void* d_ws, size_t ws_size,
                              hipStream_t stream) {
    const float* x  = (const float*)d_in[0];
    const float* Wq = (const float*)d_in[1];
    const float* bq = (const float*)d_in[2];
    const float* Wk = (const float*)d_in[3];
    const float* bk = (const float*)d_in[4];
    float* out = (float*)d_out;

    fused_kernel<<<dim3(BC), dim3(256), 0, stream>>>(x, Wq, bq, Wk, bk, out);
}